// Round 1
// baseline (362.094 us; speedup 1.0000x reference)
//
#include <hip/hip_runtime.h>
#include <hip/hip_bf16.h>
#include <cstdint>

// Problem: B=256, I=H=O=4096 single-step Elman RNN + linear + softmax.
// out[0..1048576)  = probs (fp32), out[1048576..2097152) = hn (fp32).

using short8 = __attribute__((ext_vector_type(8))) short;   // 8 bf16 in 4 VGPRs
using f32x4  = __attribute__((ext_vector_type(4))) float;

#define HDIM 4096
#define BDIM 256

// fp32 -> bf16 bits, RNE (compiler can fuse pairs into v_cvt_pk_bf16_f32)
__device__ __forceinline__ short bfbits(float f) {
    __bf16 b = (__bf16)f;
    return __builtin_bit_cast(short, b);
}

__device__ __forceinline__ short8 pack2(const float4& a, const float4& b) {
    short8 r;
    r[0] = bfbits(a.x); r[1] = bfbits(a.y); r[2] = bfbits(a.z); r[3] = bfbits(a.w);
    r[4] = bfbits(b.x); r[5] = bfbits(b.y); r[6] = bfbits(b.z); r[7] = bfbits(b.w);
    return r;
}

// MODE 0: out = tanh(A0@W0^T + A1@W1^T + bias0 + bias1)   (ntiles = 128, K split x|h)
// MODE 1: out = A0@W0^T + bias0                            (ntiles = 64)
// Tile: BM=64 x BN=64, BK=64, 256 threads = 4 waves (2x2 of 32x32 sub-tiles).
template<int MODE>
__global__ __launch_bounds__(BDIM) void rnn_gemm(
    const float* __restrict__ A0, const float* __restrict__ W0,
    const float* __restrict__ A1, const float* __restrict__ W1,
    const float* __restrict__ bias0, const float* __restrict__ bias1,
    float* __restrict__ out, int ntiles)
{
    // 2 buffers x (A 64x64 bf16 = 8KB + B 64x64 bf16 = 8KB) = 32 KB
    __shared__ __align__(16) unsigned char smem[32768];

    const int t    = threadIdx.x;
    const int m0   = blockIdx.y * 64;
    const int n0   = blockIdx.x * 64;
    const int sr   = t >> 2;         // staging row 0..63
    const int sq   = t & 3;          // 16-float chunk within row
    const int lane = t & 63;
    const int wid  = t >> 6;
    const int wr   = (wid >> 1) * 32;  // wave M offset
    const int wc   = (wid & 1) * 32;   // wave N offset
    const int lr   = lane & 15;
    const int lk   = lane >> 4;

    f32x4 acc[2][2];
#pragma unroll
    for (int i = 0; i < 2; ++i)
#pragma unroll
        for (int j = 0; j < 2; ++j) acc[i][j] = (f32x4){0.f, 0.f, 0.f, 0.f};

    float4 ra[4], rb[4];

    auto load_regs = [&](int tile) {
        const float* As = A0; const float* Ws = W0;
        if (MODE == 0 && tile >= 64) { As = A1; Ws = W1; }
        const int kb = (MODE == 0 ? (tile & 63) : tile) * 64;
        const float* ap = As + (size_t)(m0 + sr) * HDIM + kb + sq * 16;
        const float* wp = Ws + (size_t)(n0 + sr) * HDIM + kb + sq * 16;
#pragma unroll
        for (int i = 0; i < 4; ++i) ra[i] = *(const float4*)(ap + i * 4);
#pragma unroll
        for (int i = 0; i < 4; ++i) rb[i] = *(const float4*)(wp + i * 4);
    };

    // XOR-swizzle: 16B chunk c of row r lives at ((c ^ (r&7)) * 16). Bank-uniform
    // for both ds_write_b128 (stage) and ds_read_b128 (fragments).
    auto write_buf = [&](int b) {
        unsigned char* base = smem + b * 16384;
        unsigned char* arow = base + sr * 128;
        unsigned char* brow = base + 8192 + sr * 128;
        const int sw = sr & 7;
        const int c0 = sq * 2, c1 = sq * 2 + 1;
        *(short8*)(arow + ((c0 ^ sw) * 16)) = pack2(ra[0], ra[1]);
        *(short8*)(arow + ((c1 ^ sw) * 16)) = pack2(ra[2], ra[3]);
        *(short8*)(brow + ((c0 ^ sw) * 16)) = pack2(rb[0], rb[1]);
        *(short8*)(brow + ((c1 ^ sw) * 16)) = pack2(rb[2], rb[3]);
    };

    auto compute = [&](int b) {
        const unsigned char* base = smem + b * 16384;
#pragma unroll
        for (int s = 0; s < 2; ++s) {           // two K=32 sub-steps
            short8 af[2], bfr[2];
#pragma unroll
            for (int mr = 0; mr < 2; ++mr) {
                const int r = wr + mr * 16 + lr;
                af[mr] = *(const short8*)(base + r * 128 + (((s * 4 + lk) ^ (r & 7)) * 16));
            }
#pragma unroll
            for (int nr = 0; nr < 2; ++nr) {
                const int r = wc + nr * 16 + lr;
                bfr[nr] = *(const short8*)(base + 8192 + r * 128 + (((s * 4 + lk) ^ (r & 7)) * 16));
            }
#pragma unroll
            for (int mr = 0; mr < 2; ++mr)
#pragma unroll
                for (int nr = 0; nr < 2; ++nr)
                    acc[mr][nr] = __builtin_amdgcn_mfma_f32_16x16x32_bf16(
                        af[mr], bfr[nr], acc[mr][nr], 0, 0, 0);
        }
    };

    load_regs(0);
    write_buf(0);
    __syncthreads();
    for (int tile = 0; tile < ntiles; ++tile) {
        const bool more = (tile + 1 < ntiles);
        if (more) load_regs(tile + 1);      // issue early: HBM latency hides under MFMA
        compute(tile & 1);
        if (more) write_buf((tile + 1) & 1); // waits vmcnt, converts, ds_write
        __syncthreads();                     // one barrier per K-step (double-buffered)
    }

    // Epilogue. C/D layout (verified): col = lane&15, row = (lane>>4)*4 + reg.
#pragma unroll
    for (int mr = 0; mr < 2; ++mr) {
#pragma unroll
        for (int nr = 0; nr < 2; ++nr) {
            const int n = n0 + wc + nr * 16 + lr;
            const float bs = bias0[n] + (MODE == 0 ? bias1[n] : 0.f);
#pragma unroll
            for (int e = 0; e < 4; ++e) {
                const int m = m0 + wr + mr * 16 + lk * 4 + e;
                float v = acc[mr][nr][e] + bs;
                if (MODE == 0) v = tanhf(v);
                out[(size_t)m * HDIM + n] = v;
            }
        }
    }
}

// In-place numerically-stable softmax over 256 rows of 4096 fp32.
__global__ __launch_bounds__(BDIM) void softmax_inplace(float* __restrict__ p) {
    const int row = blockIdx.x;
    float* rp = p + (size_t)row * HDIM;
    const int t = threadIdx.x;

    f32x4 v[4];
#pragma unroll
    for (int i = 0; i < 4; ++i) v[i] = *(const f32x4*)(rp + (t + i * 256) * 4);

    float mx = -1e30f;
#pragma unroll
    for (int i = 0; i < 4; ++i)
#pragma unroll
        for (int j = 0; j < 4; ++j) mx = fmaxf(mx, v[i][j]);
#pragma unroll
    for (int off = 32; off; off >>= 1) mx = fmaxf(mx, __shfl_xor(mx, off));

    __shared__ float red[4];
    if ((t & 63) == 0) red[t >> 6] = mx;
    __syncthreads();
    mx = fmaxf(fmaxf(red[0], red[1]), fmaxf(red[2], red[3]));

    float sum = 0.f;
#pragma unroll
    for (int i = 0; i < 4; ++i)
#pragma unroll
        for (int j = 0; j < 4; ++j) {
            float e = __expf(v[i][j] - mx);
            v[i][j] = e;
            sum += e;
        }
#pragma unroll
    for (int off = 32; off; off >>= 1) sum += __shfl_xor(sum, off);

    __syncthreads();   // red reuse
    if ((t & 63) == 0) red[t >> 6] = sum;
    __syncthreads();
    sum = (red[0] + red[1]) + (red[2] + red[3]);

    const float inv = 1.f / sum;
#pragma unroll
    for (int i = 0; i < 4; ++i) {
        f32x4 o = v[i];
#pragma unroll
        for (int j = 0; j < 4; ++j) o[j] *= inv;
        *(f32x4*)(rp + (t + i * 256) * 4) = o;
    }
}

extern "C" void kernel_launch(void* const* d_in, const int* in_sizes, int n_in,
                              void* d_out, int out_size, void* d_ws, size_t ws_size,
                              hipStream_t stream) {
    const float* x     = (const float*)d_in[0];   // [256,4096]
    const float* h0    = (const float*)d_in[1];   // [1,256,4096]
    const float* w_ih  = (const float*)d_in[2];   // [4096,4096]
    const float* b_ih  = (const float*)d_in[3];
    const float* w_hh  = (const float*)d_in[4];
    const float* b_hh  = (const float*)d_in[5];
    const float* w_lin = (const float*)d_in[6];
    const float* b_lin = (const float*)d_in[7];

    float* probs = (float*)d_out;                       // logits then probs
    float* hn    = (float*)d_out + 256 * HDIM;          // fp32 hidden state

    dim3 grid(64, 4);  // N-blocks x M-blocks = 256 blocks
    // hn = tanh(x@w_ih^T + h@w_hh^T + b_ih + b_hh)
    rnn_gemm<0><<<grid, BDIM, 0, stream>>>(x, w_ih, h0, w_hh, b_ih, b_hh, hn, 128);
    // logits = hn@w_lin^T + b_lin  (into probs region)
    rnn_gemm<1><<<grid, BDIM, 0, stream>>>(hn, w_lin, nullptr, nullptr, b_lin, nullptr, probs, 64);
    // probs = softmax(logits) in place
    softmax_inplace<<<256, BDIM, 0, stream>>>(probs);
}

// Round 2
// 326.407 us; speedup vs baseline: 1.1093x; 1.1093x over previous
//
#include <hip/hip_runtime.h>
#include <hip/hip_bf16.h>
#include <cstdint>

// B=256, I=H=O=4096 single-step Elman RNN + linear + softmax.
// out[0..1048576) = probs (fp32), out[1048576..2097152) = hn (fp32).
//
// R2: latency-bound fix. 1024-thread blocks = 4 K-groups x 4 waves.
// Each group owns a private double-buffered LDS stage (BK=32), so the
// grid of 256 blocks now puts 16 waves/CU (4/SIMD) instead of 4/CU.

using short8 = __attribute__((ext_vector_type(8))) short;   // 8 bf16
using f32x4  = __attribute__((ext_vector_type(4))) float;

#define HDIM 4096

__device__ __forceinline__ short bfbits(float f) {
    __bf16 b = (__bf16)f;
    return __builtin_bit_cast(short, b);
}

__device__ __forceinline__ short8 pack2(const float4& a, const float4& b) {
    short8 r;
    r[0] = bfbits(a.x); r[1] = bfbits(a.y); r[2] = bfbits(a.z); r[3] = bfbits(a.w);
    r[4] = bfbits(b.x); r[5] = bfbits(b.y); r[6] = bfbits(b.z); r[7] = bfbits(b.w);
    return r;
}

// MODE 0: out = tanh(A0@W0^T + A1@W1^T + b0 + b1), K=8192 split as x|h.
//         groups 0,1 -> (A0,W0) K slices; groups 2,3 -> (A1,W1) K slices.
// MODE 1: out = A0@W0^T + b0, K=4096, groups take contiguous K quarters.
// Tile: BM=64 x BN=64. 4 waves/group arranged 2x2 of 32x32 sub-tiles.
template<int MODE>
__global__ __launch_bounds__(1024) void rnn_gemm(
    const float* __restrict__ A0, const float* __restrict__ W0,
    const float* __restrict__ A1, const float* __restrict__ W1,
    const float* __restrict__ bias0, const float* __restrict__ bias1,
    float* __restrict__ out, int steps, int kslice)
{
    // 4 groups x dbuf x (A 64x32 bf16 4KB + B 4KB) = 64 KB
    __shared__ __align__(16) unsigned char smem[65536];

    const int t    = threadIdx.x;
    const int g    = t >> 8;          // K-group 0..3
    const int tid  = t & 255;         // within-group thread
    const int m0   = blockIdx.y * 64;
    const int n0   = blockIdx.x * 64;
    const int sr   = tid >> 2;        // staging row 0..63
    const int sq   = tid & 3;         // 8-float chunk within 32-col row
    const int lane = tid & 63;        // == t&63 (groups are wave-aligned)
    const int wid  = tid >> 6;        // wave within group
    const int wr   = (wid >> 1) * 32; // wave M offset in tile
    const int wc   = (wid & 1) * 32;  // wave N offset in tile
    const int lr   = lane & 15;
    const int lk   = lane >> 4;       // K-chunk 0..3 (8 bf16 each)

    unsigned char* gsm = smem + g * 16384;   // group's private stage

    const float* As; const float* Ws; int koff;
    if (MODE == 0) {
        if (g < 2) { As = A0; Ws = W0; koff = g * kslice; }
        else       { As = A1; Ws = W1; koff = (g - 2) * kslice; }
    } else {
        As = A0; Ws = W0; koff = g * kslice;
    }

    f32x4 acc[2][2];
#pragma unroll
    for (int i = 0; i < 2; ++i)
#pragma unroll
        for (int j = 0; j < 2; ++j) acc[i][j] = (f32x4){0.f, 0.f, 0.f, 0.f};

    float4 ra[2], rb[2];

    auto load_regs = [&](int tile) {
        const float* ap = As + (size_t)(m0 + sr) * HDIM + koff + tile * 32 + sq * 8;
        const float* wp = Ws + (size_t)(n0 + sr) * HDIM + koff + tile * 32 + sq * 8;
        ra[0] = *(const float4*)ap;       ra[1] = *(const float4*)(ap + 4);
        rb[0] = *(const float4*)wp;       rb[1] = *(const float4*)(wp + 4);
    };

    // Row = 32 bf16 = 64B = 4 chunks of 16B. Swizzle chunk c -> c ^ (row&3):
    // a wave's frag read (16 rows x 1 chunk) and the stage write (16 rows x
    // 4 chunks per 64 lanes) both cover distinct 16B slots, bank-balanced.
    auto write_buf = [&](int b) {
        unsigned char* base = gsm + b * 8192;
        const int c = (sq ^ (sr & 3)) * 16;
        *(short8*)(base + sr * 64 + c)        = pack2(ra[0], ra[1]);
        *(short8*)(base + 4096 + sr * 64 + c) = pack2(rb[0], rb[1]);
    };

    auto compute = [&](int b) {
        const unsigned char* base = gsm + b * 8192;
        short8 af[2], bfr[2];
#pragma unroll
        for (int mr = 0; mr < 2; ++mr) {
            const int r = wr + mr * 16 + lr;
            af[mr] = *(const short8*)(base + r * 64 + ((lk ^ (r & 3)) * 16));
        }
#pragma unroll
        for (int nr = 0; nr < 2; ++nr) {
            const int r = wc + nr * 16 + lr;
            bfr[nr] = *(const short8*)(base + 4096 + r * 64 + ((lk ^ (r & 3)) * 16));
        }
#pragma unroll
        for (int mr = 0; mr < 2; ++mr)
#pragma unroll
            for (int nr = 0; nr < 2; ++nr)
                acc[mr][nr] = __builtin_amdgcn_mfma_f32_16x16x32_bf16(
                    af[mr], bfr[nr], acc[mr][nr], 0, 0, 0);
    };

    load_regs(0);
    write_buf(0);
    __syncthreads();
    for (int tile = 0; tile < steps; ++tile) {
        const bool more = (tile + 1 < steps);
        if (more) load_regs(tile + 1);       // issue early; latency hides under
        compute(tile & 1);                   // other groups' waves + our MFMA
        if (more) write_buf((tile + 1) & 1);
        __syncthreads();
    }

    // Cross-group reduction: groups 1..3 dump acc to LDS (reuses stage mem,
    // safe after the final barrier), group 0 sums + epilogue.
    float* red = (float*)smem;               // 3 * 4096 f32 = 48 KB
    if (g > 0) {
#pragma unroll
        for (int mr = 0; mr < 2; ++mr)
#pragma unroll
            for (int nr = 0; nr < 2; ++nr)
                *(f32x4*)&red[(g - 1) * 4096 + tid * 16 + (mr * 2 + nr) * 4] =
                    acc[mr][nr];
    }
    __syncthreads();
    if (g == 0) {
#pragma unroll
        for (int gg = 0; gg < 3; ++gg)
#pragma unroll
            for (int mr = 0; mr < 2; ++mr)
#pragma unroll
                for (int nr = 0; nr < 2; ++nr) {
                    f32x4 v = *(const f32x4*)&red[gg * 4096 + tid * 16 + (mr * 2 + nr) * 4];
                    acc[mr][nr] += v;
                }
        // C/D layout: col = lane&15, row = (lane>>4)*4 + reg.
#pragma unroll
        for (int mr = 0; mr < 2; ++mr) {
#pragma unroll
            for (int nr = 0; nr < 2; ++nr) {
                const int n = n0 + wc + nr * 16 + lr;
                const float bs = bias0[n] + (MODE == 0 ? bias1[n] : 0.f);
#pragma unroll
                for (int e = 0; e < 4; ++e) {
                    const int m = m0 + wr + mr * 16 + lk * 4 + e;
                    float v = acc[mr][nr][e] + bs;
                    if (MODE == 0) v = tanhf(v);
                    out[(size_t)m * HDIM + n] = v;
                }
            }
        }
    }
}

// In-place numerically-stable softmax over 256 rows of 4096 fp32.
__global__ __launch_bounds__(256) void softmax_inplace(float* __restrict__ p) {
    const int row = blockIdx.x;
    float* rp = p + (size_t)row * HDIM;
    const int t = threadIdx.x;

    f32x4 v[4];
#pragma unroll
    for (int i = 0; i < 4; ++i) v[i] = *(const f32x4*)(rp + (t + i * 256) * 4);

    float mx = -1e30f;
#pragma unroll
    for (int i = 0; i < 4; ++i)
#pragma unroll
        for (int j = 0; j < 4; ++j) mx = fmaxf(mx, v[i][j]);
#pragma unroll
    for (int off = 32; off; off >>= 1) mx = fmaxf(mx, __shfl_xor(mx, off));

    __shared__ float red[4];
    if ((t & 63) == 0) red[t >> 6] = mx;
    __syncthreads();
    mx = fmaxf(fmaxf(red[0], red[1]), fmaxf(red[2], red[3]));

    float sum = 0.f;
#pragma unroll
    for (int i = 0; i < 4; ++i)
#pragma unroll
        for (int j = 0; j < 4; ++j) {
            float e = __expf(v[i][j] - mx);
            v[i][j] = e;
            sum += e;
        }
#pragma unroll
    for (int off = 32; off; off >>= 1) sum += __shfl_xor(sum, off);

    __syncthreads();
    if ((t & 63) == 0) red[t >> 6] = sum;
    __syncthreads();
    sum = (red[0] + red[1]) + (red[2] + red[3]);

    const float inv = 1.f / sum;
#pragma unroll
    for (int i = 0; i < 4; ++i) {
        f32x4 o = v[i];
#pragma unroll
        for (int j = 0; j < 4; ++j) o[j] *= inv;
        *(f32x4*)(rp + (t + i * 256) * 4) = o;
    }
}

extern "C" void kernel_launch(void* const* d_in, const int* in_sizes, int n_in,
                              void* d_out, int out_size, void* d_ws, size_t ws_size,
                              hipStream_t stream) {
    const float* x     = (const float*)d_in[0];   // [256,4096]
    const float* h0    = (const float*)d_in[1];   // [1,256,4096]
    const float* w_ih  = (const float*)d_in[2];   // [4096,4096]
    const float* b_ih  = (const float*)d_in[3];
    const float* w_hh  = (const float*)d_in[4];
    const float* b_hh  = (const float*)d_in[5];
    const float* w_lin = (const float*)d_in[6];
    const float* b_lin = (const float*)d_in[7];

    float* probs = (float*)d_out;                 // logits then probs
    float* hn    = (float*)d_out + 256 * HDIM;    // fp32 hidden state

    dim3 grid(64, 4);   // N-blocks x M-blocks = 256 blocks, 16 waves each
    // hn = tanh(x@w_ih^T + h@w_hh^T + b_ih + b_hh): K=8192, 4 groups x 2048
    rnn_gemm<0><<<grid, 1024, 0, stream>>>(x, w_ih, h0, w_hh, b_ih, b_hh, hn,
                                           /*steps=*/64, /*kslice=*/2048);
    // logits = hn@w_lin^T + b_lin: K=4096, 4 groups x 1024
    rnn_gemm<1><<<grid, 1024, 0, stream>>>(hn, w_lin, nullptr, nullptr, b_lin,
                                           nullptr, probs, /*steps=*/32,
                                           /*kslice=*/1024);
    // probs = softmax(logits) in place
    softmax_inplace<<<256, 256, 0, stream>>>(probs);
}

// Round 4
// 270.560 us; speedup vs baseline: 1.3383x; 1.2064x over previous
//
#include <hip/hip_runtime.h>
#include <hip/hip_bf16.h>
#include <cstdint>

// B=256, I=H=O=4096 single-step Elman RNN + linear + softmax.
// out[0..1048576) = probs (fp32), out[1048576..2097152) = hn (fp32).
//
// R3 (resubmit after infra timeout): latency + cache-traffic fix.
//  - BM=BN=128 tiles (aggregate L2/L3 traffic 1 GB -> 512 MB per GEMM)
//  - K split across 4 blocks; fp32 atomicAdd into zeroed d_out regions
//  - global_load_lds dwordx4 staging of fp32 tiles (no reg round-trip),
//    pre-swizzled global source + XOR-swizzled ds_read (rule #21)
//  - T3/T4 2-phase pipeline, counted vmcnt(4) (never 0 mid-loop)
//  - bf16 cvt at frag-read time; bias/tanh/softmax in epilogue kernels

using short8 = __attribute__((ext_vector_type(8))) short;
using f32x4  = __attribute__((ext_vector_type(4))) float;

#define HDIM 4096

__device__ __forceinline__ short bfbits(float f) {
    __bf16 b = (__bf16)f;
    return __builtin_bit_cast(short, b);
}
__device__ __forceinline__ short8 pack8(f32x4 a, f32x4 b) {
    short8 r;
    r[0] = bfbits(a[0]); r[1] = bfbits(a[1]); r[2] = bfbits(a[2]); r[3] = bfbits(a[3]);
    r[4] = bfbits(b[0]); r[5] = bfbits(b[1]); r[6] = bfbits(b[2]); r[7] = bfbits(b[3]);
    return r;
}

// Async global->LDS, 16B per lane. LDS dest is wave-uniform base + lane*16
// (HW semantics, m104) so we pass the lane-0 address; global src is per-lane.
__device__ __forceinline__ void gld_lds16(const float* g, const float* l) {
    __builtin_amdgcn_global_load_lds(
        (const __attribute__((address_space(1))) void*)g,
        (__attribute__((address_space(3))) void*)l, 16, 0, 0);
}

// One K-slice partial of out += A[128 rows] @ W[128 rows]^T, atomicAdd'ed.
// MODE 0: ks 0,1 -> (A0,W0), ks 2,3 -> (A1,W1)  (concat-K RNN cell)
// MODE 1: ks 0..3 -> contiguous quarters of K=4096
// Block: 512 thr = 8 waves (4M x 2N), wave-tile 32x64. BK=32 fp32 in LDS.
template<int MODE>
__global__ __launch_bounds__(512) void rnn_gemm(
    const float* __restrict__ A0, const float* __restrict__ W0,
    const float* __restrict__ A1, const float* __restrict__ W1,
    float* __restrict__ out, int steps, int kslice)
{
    // 2 bufs x (A 128x32 f32 16KB + B 16KB) = 64 KB
    __shared__ __align__(16) float smem[16384];

    const int t    = threadIdx.x;
    const int lane = t & 63;
    const int wid  = t >> 6;
    const int bid  = blockIdx.x;
    // grp = XCD-resident group (dispatch round-robins bid%8 across XCDs):
    // all 32 n-tiles of one (mtile,ks) share an XCD -> A-panel L2-hot.
    const int grp   = bid & 7;
    const int ntile = bid >> 3;      // 0..31
    const int mtile = grp >> 2;      // 0..1
    const int ks    = grp & 3;       // K-slice 0..3
    const int m0 = mtile * 128, n0 = ntile * 128;
    const int wr = (wid & 3) * 32;   // wave M offset
    const int wc = (wid >> 2) * 64;  // wave N offset
    const int lr = lane & 15;
    const int lk = lane >> 4;        // 0..3

    const float* As; const float* Ws; int koff;
    if (MODE == 0) {
        if (ks < 2) { As = A0; Ws = W0; koff = ks * kslice; }
        else        { As = A1; Ws = W1; koff = (ks - 2) * kslice; }
    } else { As = A0; Ws = W0; koff = ks * kslice; }

    // Staging: per wave per buf-fill: 4 gld_lds16 (A x2, B x2), 1 KB each.
    // LDS linear; source column pre-swizzled so ds_read can XOR-deswizzle:
    // LDS slot (row, c) holds global 16B-chunk (c ^ (row&7)).
    const int srow = lane >> 3;             // row&7 within the 8-row stripe
    const int gc   = (lane & 7) ^ srow;     // pre-swizzled source chunk

    auto stage = [&](int b, int step) {
        const int kb = koff + step * 32 + gc * 4;
        const float* lA = &smem[b * 8192 + wid * 512];
        const float* lB = &smem[b * 8192 + 4096 + wid * 512];
#pragma unroll
        for (int i = 0; i < 2; ++i) {
            const int row = wid * 16 + i * 8 + srow;
            gld_lds16(As + (size_t)(m0 + row) * HDIM + kb, lA + i * 256);
            gld_lds16(Ws + (size_t)(n0 + row) * HDIM + kb, lB + i * 256);
        }
    };

    f32x4 acc[2][4];
#pragma unroll
    for (int i = 0; i < 2; ++i)
#pragma unroll
        for (int j = 0; j < 4; ++j) acc[i][j] = (f32x4){0.f, 0.f, 0.f, 0.f};

    auto compute = [&](int b) {
        const float* Ab = &smem[b * 8192];
        const float* Bb = &smem[b * 8192 + 4096];
        short8 af[2], bf[4];
#pragma unroll
        for (int mr = 0; mr < 2; ++mr) {
            const int r = wr + mr * 16 + lr;
            const float* rp = Ab + r * 32;
            f32x4 lo = *(const f32x4*)(rp + ((2 * lk)     ^ (r & 7)) * 4);
            f32x4 hi = *(const f32x4*)(rp + ((2 * lk + 1) ^ (r & 7)) * 4);
            af[mr] = pack8(lo, hi);
        }
#pragma unroll
        for (int nr = 0; nr < 4; ++nr) {
            const int r = wc + nr * 16 + lr;
            const float* rp = Bb + r * 32;
            f32x4 lo = *(const f32x4*)(rp + ((2 * lk)     ^ (r & 7)) * 4);
            f32x4 hi = *(const f32x4*)(rp + ((2 * lk + 1) ^ (r & 7)) * 4);
            bf[nr] = pack8(lo, hi);
        }
#pragma unroll
        for (int mr = 0; mr < 2; ++mr)
#pragma unroll
            for (int nr = 0; nr < 4; ++nr)
                acc[mr][nr] = __builtin_amdgcn_mfma_f32_16x16x32_bf16(
                    af[mr], bf[nr], acc[mr][nr], 0, 0, 0);
    };

    // T3/T4 depth-2 pipeline. vmcnt counts per-wave (4 DMA per stage);
    // barrier makes per-wave waits collective. Never drain to 0 mid-loop.
    stage(0, 0);
    stage(1, 1);
    asm volatile("s_waitcnt vmcnt(4)" ::: "memory");  // buf0 ready, buf1 flying
    __builtin_amdgcn_s_barrier();
    __builtin_amdgcn_sched_barrier(0);
    for (int tt = 0; tt < steps; ++tt) {
        compute(tt & 1);                    // lgkm waits inserted by compiler
        __builtin_amdgcn_s_barrier();       // all waves done reading this buf
        __builtin_amdgcn_sched_barrier(0);
        if (tt + 2 < steps) {
            stage(tt & 1, tt + 2);          // refill just-consumed buf
            asm volatile("s_waitcnt vmcnt(4)" ::: "memory");  // next buf ready
        } else {
            asm volatile("s_waitcnt vmcnt(0)" ::: "memory");  // final drain
        }
        __builtin_amdgcn_s_barrier();
        __builtin_amdgcn_sched_barrier(0);
    }

    // Epilogue: atomic accumulate partial tile into out (zeroed by memset).
    // C/D layout: col = lane&15, row = (lane>>4)*4 + reg.
#pragma unroll
    for (int mr = 0; mr < 2; ++mr)
#pragma unroll
        for (int nr = 0; nr < 4; ++nr) {
            const int n = n0 + wc + nr * 16 + lr;
#pragma unroll
            for (int e = 0; e < 4; ++e) {
                const int m = m0 + wr + mr * 16 + lk * 4 + e;
                atomicAdd(&out[(size_t)m * HDIM + n], acc[mr][nr][e]);
            }
        }
}

// hn = tanh(hn_acc + b_ih + b_hh), elementwise over [256][4096].
__global__ __launch_bounds__(256) void finish_hn(
    float* __restrict__ hn, const float* __restrict__ b_ih,
    const float* __restrict__ b_hh)
{
    const int idx = blockIdx.x * 256 + threadIdx.x;   // f32x4 index
    const int col = (idx & 1023) * 4;
    f32x4 v  = *((const f32x4*)hn + idx);
    f32x4 bi = *(const f32x4*)(b_ih + col);
    f32x4 bh = *(const f32x4*)(b_hh + col);
#pragma unroll
    for (int j = 0; j < 4; ++j) v[j] = tanhf(v[j] + bi[j] + bh[j]);
    *((f32x4*)hn + idx) = v;
}

// probs = softmax(logits + b_lin) per row, in place.
__global__ __launch_bounds__(256) void softmax_bias(
    float* __restrict__ p, const float* __restrict__ bl)
{
    const int row = blockIdx.x;
    float* rp = p + (size_t)row * HDIM;
    const int t = threadIdx.x;

    f32x4 v[4];
#pragma unroll
    for (int i = 0; i < 4; ++i) {
        const int c = t + i * 256;
        v[i] = *(const f32x4*)(rp + c * 4);
        f32x4 b = *(const f32x4*)(bl + c * 4);
        v[i] += b;
    }

    float mx = -1e30f;
#pragma unroll
    for (int i = 0; i < 4; ++i)
#pragma unroll
        for (int j = 0; j < 4; ++j) mx = fmaxf(mx, v[i][j]);
#pragma unroll
    for (int off = 32; off; off >>= 1) mx = fmaxf(mx, __shfl_xor(mx, off));

    __shared__ float red[4];
    if ((t & 63) == 0) red[t >> 6] = mx;
    __syncthreads();
    mx = fmaxf(fmaxf(red[0], red[1]), fmaxf(red[2], red[3]));

    float sum = 0.f;
#pragma unroll
    for (int i = 0; i < 4; ++i)
#pragma unroll
        for (int j = 0; j < 4; ++j) {
            float e = __expf(v[i][j] - mx);
            v[i][j] = e;
            sum += e;
        }
#pragma unroll
    for (int off = 32; off; off >>= 1) sum += __shfl_xor(sum, off);

    __syncthreads();
    if ((t & 63) == 0) red[t >> 6] = sum;
    __syncthreads();
    sum = (red[0] + red[1]) + (red[2] + red[3]);

    const float inv = 1.f / sum;
#pragma unroll
    for (int i = 0; i < 4; ++i) {
        f32x4 o = v[i];
#pragma unroll
        for (int j = 0; j < 4; ++j) o[j] *= inv;
        *(f32x4*)(rp + (t + i * 256) * 4) = o;
    }
}

extern "C" void kernel_launch(void* const* d_in, const int* in_sizes, int n_in,
                              void* d_out, int out_size, void* d_ws, size_t ws_size,
                              hipStream_t stream) {
    const float* x     = (const float*)d_in[0];   // [256,4096]
    const float* h0    = (const float*)d_in[1];   // [1,256,4096]
    const float* w_ih  = (const float*)d_in[2];   // [4096,4096]
    const float* b_ih  = (const float*)d_in[3];
    const float* w_hh  = (const float*)d_in[4];
    const float* b_hh  = (const float*)d_in[5];
    const float* w_lin = (const float*)d_in[6];
    const float* b_lin = (const float*)d_in[7];

    float* probs = (float*)d_out;                 // logits acc, then probs
    float* hn    = (float*)d_out + 256 * HDIM;    // hn acc, then tanh'd

    // Zero both accumulation regions (d_out is 0xAA-poisoned each launch).
    hipMemsetAsync(d_out, 0, (size_t)2 * 256 * HDIM * sizeof(float), stream);

    // hn_acc += x@w_ih^T (ks 0,1) + h@w_hh^T (ks 2,3); 64 steps of BK=32
    rnn_gemm<0><<<256, 512, 0, stream>>>(x, w_ih, h0, w_hh, hn, 64, 2048);
    finish_hn<<<1024, 256, 0, stream>>>(hn, b_ih, b_hh);
    // logits_acc += hn@w_lin^T; K=4096 in 4 slices of 1024; 32 steps
    rnn_gemm<1><<<256, 512, 0, stream>>>(hn, w_lin, nullptr, nullptr, probs, 32, 1024);
    softmax_bias<<<256, 256, 0, stream>>>(probs, b_lin);
}

// Round 5
// 261.853 us; speedup vs baseline: 1.3828x; 1.0333x over previous
//
#include <hip/hip_runtime.h>
#include <hip/hip_bf16.h>
#include <cstdint>

// B=256, I=H=O=4096 single-step Elman RNN + linear + softmax.
// out[0..1048576) = probs (fp32), out[1048576..2097152) = hn (fp32).
//
// R5: LDS-pipe + latency fix on top of R4's 128x128/K-split/atomic design.
//  - bf16 LDS tiles via reg-staging (global f32 -> reg -> cvt_pk -> ds_write):
//    halves LDS write+read traffic, removes ALL read-side cvt (frags load
//    short8 directly). cvt once per element instead of 2-4x.
//  - BK=64 (32 steps), chunk^(row&7) XOR swizzle on 128B bf16 rows, applied
//    identically on ds_write and ds_read (both-sides rule, analytic 2-way).
//  - T14 issue-early/write-late, depth-2 over BK=64: loads for t+2 issued at
//    top of iter t, vmcnt(8) counted wait, lgkmcnt(0)+raw barrier (1/step,
//    no vmcnt drain at barrier).
//  - Unroll-2 with named reg sets P/Q (no runtime-indexed staging arrays).

using short8 = __attribute__((ext_vector_type(8))) short;
using f32x4  = __attribute__((ext_vector_type(4))) float;

#define HDIM 4096

__device__ __forceinline__ short bfbits(float f) {
    __bf16 b = (__bf16)f;
    return __builtin_bit_cast(short, b);
}
__device__ __forceinline__ short8 pack8(const float4& a, const float4& b) {
    short8 r;
    r[0] = bfbits(a.x); r[1] = bfbits(a.y); r[2] = bfbits(a.z); r[3] = bfbits(a.w);
    r[4] = bfbits(b.x); r[5] = bfbits(b.y); r[6] = bfbits(b.z); r[7] = bfbits(b.w);
    return r;
}

// One K-slice partial of out += A[128 rows] @ W[128 rows]^T, atomicAdd'ed.
// MODE 0: ks 0,1 -> (A0,W0), ks 2,3 -> (A1,W1)  (concat-K RNN cell)
// MODE 1: ks 0..3 -> contiguous quarters of K=4096
// Block: 512 thr = 8 waves (4M x 2N), wave-tile 32x64. BK=64 bf16 in LDS.
template<int MODE>
__global__ __launch_bounds__(512) void rnn_gemm(
    const float* __restrict__ A0, const float* __restrict__ W0,
    const float* __restrict__ A1, const float* __restrict__ W1,
    float* __restrict__ out, int steps, int kslice)
{
    // 2 bufs x (A 128x64 bf16 16KB + B 16KB) = 64 KB
    __shared__ __align__(16) unsigned char smem[65536];

    const int t    = threadIdx.x;
    const int lane = t & 63;
    const int wid  = t >> 6;
    const int bid  = blockIdx.x;
    // bid%8 round-robins across XCDs: pin each (mtile,ks) to one XCD so its
    // 32 ntile-blocks share the 1 MB A-panel in that XCD's L2.
    const int grp   = bid & 7;
    const int ntile = bid >> 3;      // 0..31
    const int mtile = grp >> 2;      // 0..1
    const int ks    = grp & 3;       // K-slice 0..3
    const int m0 = mtile * 128, n0 = ntile * 128;
    const int wr = (wid & 3) * 32;   // wave M offset
    const int wc = (wid >> 2) * 64;  // wave N offset
    const int lr = lane & 15;
    const int lk = lane >> 4;        // 0..3

    const float* As; const float* Ws; int koff;
    if (MODE == 0) {
        if (ks < 2) { As = A0; Ws = W0; koff = ks * kslice; }
        else        { As = A1; Ws = W1; koff = (ks - 2) * kslice; }
    } else { As = A0; Ws = W0; koff = ks * kslice; }

    // Staging assignment: wave stages rows [wid*16, wid*16+16) of A and B.
    // lane: sub-row lr8 = lane>>3 (+0/+8 over i), 16B-bf16 chunk c = lane&7.
    const int lr8 = lane >> 3;
    const int ch  = lane & 7;
    const int rbase = wid * 16;

    // P/Q staging register sets (named, statically indexed).
    float4 pa0, pa1, pa2, pa3, pb0, pb1, pb2, pb3;
    float4 qa0, qa1, qa2, qa3, qb0, qb1, qb2, qb3;

#define ISSUE(A0r, A1r, A2r, A3r, B0r, B1r, B2r, B3r, step)                     \
    {                                                                           \
        const int kb = koff + (step) * 64 + ch * 8;                             \
        const float* ap = As + (size_t)(m0 + rbase + lr8) * HDIM + kb;          \
        const float* wp = Ws + (size_t)(n0 + rbase + lr8) * HDIM + kb;          \
        A0r = *(const float4*)(ap);            A1r = *(const float4*)(ap + 4);  \
        A2r = *(const float4*)(ap + 8 * HDIM); A3r = *(const float4*)(ap + 8 * HDIM + 4); \
        B0r = *(const float4*)(wp);            B1r = *(const float4*)(wp + 4);  \
        B2r = *(const float4*)(wp + 8 * HDIM); B3r = *(const float4*)(wp + 8 * HDIM + 4); \
    }

    // bf16 row = 64 elems = 128 B = 8 chunks of 16B; slot = ch ^ (row&7).
#define WRITEBUF(A0r, A1r, A2r, A3r, B0r, B1r, B2r, B3r, b)                     \
    {                                                                           \
        unsigned char* base = smem + (b) * 32768;                               \
        const int r0 = rbase + lr8, r1 = rbase + 8 + lr8;                       \
        const int o0 = r0 * 128 + ((ch ^ (r0 & 7)) * 16);                       \
        const int o1 = r1 * 128 + ((ch ^ (r1 & 7)) * 16);                       \
        *(short8*)(base + o0)         = pack8(A0r, A1r);                        \
        *(short8*)(base + o1)         = pack8(A2r, A3r);                        \
        *(short8*)(base + 16384 + o0) = pack8(B0r, B1r);                        \
        *(short8*)(base + 16384 + o1) = pack8(B2r, B3r);                        \
    }

    f32x4 acc[2][4];
#pragma unroll
    for (int i = 0; i < 2; ++i)
#pragma unroll
        for (int j = 0; j < 4; ++j) acc[i][j] = (f32x4){0.f, 0.f, 0.f, 0.f};

    auto compute = [&](int b) {
        const unsigned char* base = smem + b * 32768;
#pragma unroll
        for (int s = 0; s < 2; ++s) {          // two K=32 sub-steps of BK=64
            short8 af[2], bv[4];
#pragma unroll
            for (int mr = 0; mr < 2; ++mr) {
                const int r = wr + mr * 16 + lr;
                af[mr] = *(const short8*)(base + r * 128 + (((s * 4 + lk) ^ (r & 7)) * 16));
            }
#pragma unroll
            for (int nr = 0; nr < 4; ++nr) {
                const int r = wc + nr * 16 + lr;
                bv[nr] = *(const short8*)(base + 16384 + r * 128 + (((s * 4 + lk) ^ (r & 7)) * 16));
            }
#pragma unroll
            for (int mr = 0; mr < 2; ++mr)
#pragma unroll
                for (int nr = 0; nr < 4; ++nr)
                    acc[mr][nr] = __builtin_amdgcn_mfma_f32_16x16x32_bf16(
                        af[mr], bv[nr], acc[mr][nr], 0, 0, 0);
        }
    };

    // Prologue: P<-step0, Q<-step1; wait P (8 newer Q loads outstanding).
    ISSUE(pa0, pa1, pa2, pa3, pb0, pb1, pb2, pb3, 0);
    ISSUE(qa0, qa1, qa2, qa3, qb0, qb1, qb2, qb3, 1);
    asm volatile("s_waitcnt vmcnt(8)" ::: "memory");
    WRITEBUF(pa0, pa1, pa2, pa3, pb0, pb1, pb2, pb3, 0);
    asm volatile("s_waitcnt lgkmcnt(0)" ::: "memory");
    __builtin_amdgcn_s_barrier();

    // Steady state (steps even): buf parity == step parity.
    for (int tt = 0; tt < steps; tt += 2) {
        // iter tt: compute buf0(step tt); P free -> issue tt+2; write Q->buf1
        if (tt + 2 < steps) ISSUE(pa0, pa1, pa2, pa3, pb0, pb1, pb2, pb3, tt + 2);
        compute(0);
        if (tt + 2 < steps) { asm volatile("s_waitcnt vmcnt(8)" ::: "memory"); }
        else                { asm volatile("s_waitcnt vmcnt(0)" ::: "memory"); }
        WRITEBUF(qa0, qa1, qa2, qa3, qb0, qb1, qb2, qb3, 1);
        asm volatile("s_waitcnt lgkmcnt(0)" ::: "memory");
        __builtin_amdgcn_s_barrier();

        // iter tt+1: compute buf1(step tt+1); Q free -> issue tt+3; write P->buf0
        if (tt + 3 < steps) ISSUE(qa0, qa1, qa2, qa3, qb0, qb1, qb2, qb3, tt + 3);
        compute(1);
        if (tt + 2 < steps) {
            if (tt + 3 < steps) { asm volatile("s_waitcnt vmcnt(8)" ::: "memory"); }
            else                { asm volatile("s_waitcnt vmcnt(0)" ::: "memory"); }
            WRITEBUF(pa0, pa1, pa2, pa3, pb0, pb1, pb2, pb3, 0);
            asm volatile("s_waitcnt lgkmcnt(0)" ::: "memory");
        }
        __builtin_amdgcn_s_barrier();
    }
#undef ISSUE
#undef WRITEBUF

    // Epilogue: atomic accumulate partial tile (out zeroed by memset).
    // C/D layout: col = lane&15, row = (lane>>4)*4 + reg.
#pragma unroll
    for (int mr = 0; mr < 2; ++mr)
#pragma unroll
        for (int nr = 0; nr < 4; ++nr) {
            const int n = n0 + wc + nr * 16 + lr;
#pragma unroll
            for (int e = 0; e < 4; ++e) {
                const int m = m0 + wr + mr * 16 + lk * 4 + e;
                atomicAdd(&out[(size_t)m * HDIM + n], acc[mr][nr][e]);
            }
        }
}

// hn = tanh(hn_acc + b_ih + b_hh), elementwise over [256][4096].
__global__ __launch_bounds__(256) void finish_hn(
    float* __restrict__ hn, const float* __restrict__ b_ih,
    const float* __restrict__ b_hh)
{
    const int idx = blockIdx.x * 256 + threadIdx.x;   // f32x4 index
    const int col = (idx & 1023) * 4;
    f32x4 v  = *((const f32x4*)hn + idx);
    f32x4 bi = *(const f32x4*)(b_ih + col);
    f32x4 bh = *(const f32x4*)(b_hh + col);
#pragma unroll
    for (int j = 0; j < 4; ++j) v[j] = tanhf(v[j] + bi[j] + bh[j]);
    *((f32x4*)hn + idx) = v;
}

// probs = softmax(logits + b_lin) per row, in place.
__global__ __launch_bounds__(256) void softmax_bias(
    float* __restrict__ p, const float* __restrict__ bl)
{
    const int row = blockIdx.x;
    float* rp = p + (size_t)row * HDIM;
    const int t = threadIdx.x;

    f32x4 v[4];
#pragma unroll
    for (int i = 0; i < 4; ++i) {
        const int c = t + i * 256;
        v[i] = *(const f32x4*)(rp + c * 4);
        f32x4 b = *(const f32x4*)(bl + c * 4);
        v[i] += b;
    }

    float mx = -1e30f;
#pragma unroll
    for (int i = 0; i < 4; ++i)
#pragma unroll
        for (int j = 0; j < 4; ++j) mx = fmaxf(mx, v[i][j]);
#pragma unroll
    for (int off = 32; off; off >>= 1) mx = fmaxf(mx, __shfl_xor(mx, off));

    __shared__ float red[4];
    if ((t & 63) == 0) red[t >> 6] = mx;
    __syncthreads();
    mx = fmaxf(fmaxf(red[0], red[1]), fmaxf(red[2], red[3]));

    float sum = 0.f;
#pragma unroll
    for (int i = 0; i < 4; ++i)
#pragma unroll
        for (int j = 0; j < 4; ++j) {
            float e = __expf(v[i][j] - mx);
            v[i][j] = e;
            sum += e;
        }
#pragma unroll
    for (int off = 32; off; off >>= 1) sum += __shfl_xor(sum, off);

    __syncthreads();
    if ((t & 63) == 0) red[t >> 6] = sum;
    __syncthreads();
    sum = (red[0] + red[1]) + (red[2] + red[3]);

    const float inv = 1.f / sum;
#pragma unroll
    for (int i = 0; i < 4; ++i) {
        f32x4 o = v[i];
#pragma unroll
        for (int j = 0; j < 4; ++j) o[j] *= inv;
        *(f32x4*)(rp + (t + i * 256) * 4) = o;
    }
}

extern "C" void kernel_launch(void* const* d_in, const int* in_sizes, int n_in,
                              void* d_out, int out_size, void* d_ws, size_t ws_size,
                              hipStream_t stream) {
    const float* x     = (const float*)d_in[0];   // [256,4096]
    const float* h0    = (const float*)d_in[1];   // [1,256,4096]
    const float* w_ih  = (const float*)d_in[2];   // [4096,4096]
    const float* b_ih  = (const float*)d_in[3];
    const float* w_hh  = (const float*)d_in[4];
    const float* b_hh  = (const float*)d_in[5];
    const float* w_lin = (const float*)d_in[6];
    const float* b_lin = (const float*)d_in[7];

    float* probs = (float*)d_out;                 // logits acc, then probs
    float* hn    = (float*)d_out + 256 * HDIM;    // hn acc, then tanh'd

    // Zero both accumulation regions (d_out is 0xAA-poisoned each launch).
    hipMemsetAsync(d_out, 0, (size_t)2 * 256 * HDIM * sizeof(float), stream);

    // hn_acc += x@w_ih^T (ks 0,1) + h@w_hh^T (ks 2,3); 32 steps of BK=64
    rnn_gemm<0><<<256, 512, 0, stream>>>(x, w_ih, h0, w_hh, hn, 32, 2048);
    finish_hn<<<1024, 256, 0, stream>>>(hn, b_ih, b_hh);
    // logits_acc += hn@w_lin^T; K=4096 in 4 slices of 1024; 16 steps
    rnn_gemm<1><<<256, 512, 0, stream>>>(hn, w_lin, nullptr, nullptr, probs, 16, 1024);
    softmax_bias<<<256, 256, 0, stream>>>(probs, b_lin);
}